// Round 2
// baseline (13830.750 us; speedup 1.0000x reference)
//
#include <hip/hip_runtime.h>

// Packed-LSTM (B=64, S=2048, H=512, V=25) + linear head — round 2.
// One WAVE per workgroup (64 threads), 256 WGs = 4 length-sorted groups x 64
// slices of 8 hidden units. No __syncthreads in the step loop: flags polled
// lane-parallel with agent-acquire (buffer_inv), A-fragments loaded straight
// from LLC into registers (plain dwordx4 after the acquire), W_hh slice
// resident in VGPRs as bf16 B-fragments, in-wave D->cell transpose via LDS
// (in-order LDS pipe, waitcnt only). h published as relaxed agent atomics
// (write-through LLC); per-WG flag posted with release (drains vmcnt).
// Row mapping puts all 4 gates of a WG's 8 units inside its own 32-row slice
// so the cell update needs no cross-WG gate exchange.

#define VOCAB 25
#define HIDDEN 512
#define BATCH 64
#define SEQ 2048
#define GB 16   // batches per group
#define NG 4    // groups
#define WPG 64  // wave-WGs per group
#define UPW 8   // hidden units per WG
#define NT 64

typedef short s16x8 __attribute__((ext_vector_type(8)));
typedef float f32x4 __attribute__((ext_vector_type(4)));

__device__ inline unsigned short f2bf(float x) {
  unsigned u = __float_as_uint(x);
  u += 0x7fffu + ((u >> 16) & 1u);  // RNE
  return (unsigned short)(u >> 16);
}
__device__ inline float sigf(float x) { return 1.0f / (1.0f + __expf(-x)); }
__device__ inline float tanh_fast(float x) { return 2.0f / (1.0f + __expf(-2.0f * x)) - 1.0f; }

__global__ void prep_kernel(int* flags, float* out) {
  const int i = blockIdx.x * blockDim.x + threadIdx.x;
  if (i < NG * WPG * 16) flags[i] = 0;
  if (i < BATCH) out[i] = 0.f;
}

__global__ __launch_bounds__(NT, 1) void lstm_wave(
    const int* __restrict__ tokens, const int* __restrict__ lengths,
    const float* __restrict__ W_ih, const float* __restrict__ W_hh,
    const float* __restrict__ b_ih, const float* __restrict__ b_hh,
    const float* __restrict__ fc_w, const float* __restrict__ fc_b,
    float* __restrict__ out, int* flags, unsigned short* hglob) {
  const int tid = threadIdx.x;  // == lane
  const int bid = blockIdx.x;
  // XCD swizzle: group g on XCDs {2g,2g+1}
  const int x = bid & 7;
  const int g = x >> 1;                       // 0..3
  const int w = ((bid >> 3) << 1) | (x & 1);  // 0..63

  __shared__ int lenAll[BATCH];
  __shared__ int order_[BATCH];
  __shared__ int gIdxS[GB];
  __shared__ int gLenS[GB];
  __shared__ float xgt[VOCAB][33];   // input projection for this slice (rl = gate*8+unit)
  __shared__ float gatesS[32][17];   // D transpose scratch [rl][batch]

  lenAll[tid] = lengths[tid];
  __syncthreads();
  {  // stable argsort(-lengths)
    const int L = lenAll[tid];
    int r = 0;
    for (int j = 0; j < BATCH; ++j) {
      const int lj = lenAll[j];
      r += ((lj > L) || (lj == L && j < tid)) ? 1 : 0;
    }
    order_[r] = tid;
  }
  __syncthreads();
  if (tid < GB) {
    const int oi = order_[g * GB + tid];
    gIdxS[tid] = oi;
    gLenS[tid] = lenAll[oi];
  }
  for (int i = tid; i < VOCAB * 32; i += NT) {
    const int v = i >> 5, rl = i & 31;  // rl: gate = rl>>3, unit = rl&7
    const int rg = (rl >> 3) * HIDDEN + w * UPW + (rl & 7);
    xgt[v][rl] = W_ih[rg * VOCAB + v] + b_ih[rg] + b_hh[rg];
  }
  __syncthreads();

  const int m16 = tid & 15, quad = tid >> 4;  // MFMA lane roles
  const int cb = tid >> 2, cq = tid & 3;      // cell roles: batch, unit-pair
  const int u0 = 2 * cq;
  const int T = gLenS[0];
  const int myLen = gLenS[cb];
  const int* tokPtr = tokens + (size_t)gIdxS[cb] * SEQ;

  // B fragments: 2 n-tiles x 16 k-chunks, bf16 in VGPRs (128 VGPRs/lane)
  s16x8 Bf[2][16];
#pragma unroll
  for (int tile = 0; tile < 2; ++tile) {
    const int rl = tile * 16 + m16;
    const int rg = (rl >> 3) * HIDDEN + w * UPW + (rl & 7);
    const float* wr = W_hh + (size_t)rg * HIDDEN;
#pragma unroll
    for (int kt = 0; kt < 16; ++kt) {
      const float* p = wr + kt * 32 + quad * 8;
#pragma unroll
      for (int e = 0; e < 8; ++e) Bf[tile][kt][e] = (short)f2bf(p[e]);
    }
  }

  float c0 = 0.f, c1 = 0.f, h0 = 0.f, h1 = 0.f;
  int* myFlag = flags + (g * WPG + w) * 16;
  int* pollFlag = flags + (g * WPG + tid) * 16;  // lane l polls slice l's flag
  const size_t grpStride = (size_t)GB * HIDDEN;  // shorts

  for (int t = 0; t < T; ++t) {
    const int tok = tokPtr[t];
    s16x8 A[16];
    if (t > 0) {
      int v;
      do {  // acquire -> buffer_inv: plain loads below see LLC-fresh data
        v = __hip_atomic_load(pollFlag, __ATOMIC_ACQUIRE, __HIP_MEMORY_SCOPE_AGENT);
      } while (!__all(v >= t));
      const unsigned short* hb = hglob + ((size_t)(t & 1) * NG + g) * grpStride +
                                 (size_t)m16 * HIDDEN + quad * 8;
#pragma unroll
      for (int kt = 0; kt < 16; ++kt) A[kt] = *(const s16x8*)(hb + kt * 32);
    } else {
#pragma unroll
      for (int kt = 0; kt < 16; ++kt) A[kt] = (s16x8){0, 0, 0, 0, 0, 0, 0, 0};
    }

    f32x4 a0a = {0.f, 0.f, 0.f, 0.f}, a0b = {0.f, 0.f, 0.f, 0.f};
    f32x4 a1a = {0.f, 0.f, 0.f, 0.f}, a1b = {0.f, 0.f, 0.f, 0.f};
#pragma unroll
    for (int kt = 0; kt < 16; kt += 2) {  // 4 independent accumulation chains
      a0a = __builtin_amdgcn_mfma_f32_16x16x32_bf16(A[kt], Bf[0][kt], a0a, 0, 0, 0);
      a1a = __builtin_amdgcn_mfma_f32_16x16x32_bf16(A[kt], Bf[1][kt], a1a, 0, 0, 0);
      a0b = __builtin_amdgcn_mfma_f32_16x16x32_bf16(A[kt + 1], Bf[0][kt + 1], a0b, 0, 0, 0);
      a1b = __builtin_amdgcn_mfma_f32_16x16x32_bf16(A[kt + 1], Bf[1][kt + 1], a1b, 0, 0, 0);
    }
    const f32x4 d0 = a0a + a0b, d1 = a1a + a1b;
    // D layout: row(batch)=quad*4+v, col(gate-row)=m16. In-wave transpose via LDS.
#pragma unroll
    for (int v = 0; v < 4; ++v) {
      gatesS[m16][quad * 4 + v] = d0[v];
      gatesS[16 + m16][quad * 4 + v] = d1[v];
    }
    const float* xr = &xgt[tok][0];
    float p0[4], p1[4];
#pragma unroll
    for (int gg = 0; gg < 4; ++gg) {
      p0[gg] = gatesS[gg * 8 + u0][cb] + xr[gg * 8 + u0];
      p1[gg] = gatesS[gg * 8 + u0 + 1][cb] + xr[gg * 8 + u0 + 1];
    }
    if (t < myLen) {  // freeze state past sequence end
      float ii = sigf(p0[0]), ff = sigf(p0[1]), gv = tanh_fast(p0[2]), oo = sigf(p0[3]);
      c0 = ff * c0 + ii * gv;
      h0 = oo * tanh_fast(c0);
      ii = sigf(p1[0]); ff = sigf(p1[1]); gv = tanh_fast(p1[2]); oo = sigf(p1[3]);
      c1 = ff * c1 + ii * gv;
      h1 = oo * tanh_fast(c1);
    }
    if (t + 1 < T) {
      const unsigned val = (unsigned)f2bf(h0) | ((unsigned)f2bf(h1) << 16);
      unsigned* hp = (unsigned*)(hglob + ((size_t)((t + 1) & 1) * NG + g) * grpStride +
                                 (size_t)cb * HIDDEN + w * UPW + u0);
      __hip_atomic_store(hp, val, __ATOMIC_RELAXED, __HIP_MEMORY_SCOPE_AGENT);
      if (tid == 0)  // release: wave-wide vmcnt drain orders all lanes' h stores
        __hip_atomic_store(myFlag, t + 1, __ATOMIC_RELEASE, __HIP_MEMORY_SCOPE_AGENT);
    }
  }

  // out[g*16+b] = h . fc_w + fc_b (sorted order)
  float part = h0 * fc_w[w * UPW + u0] + h1 * fc_w[w * UPW + u0 + 1];
  part += __shfl_xor(part, 1);
  part += __shfl_xor(part, 2);
  if (cq == 0) {
    if (w == 0) part += fc_b[0];
    atomicAdd(&out[g * GB + cb], part);
  }
}

extern "C" void kernel_launch(void* const* d_in, const int* in_sizes, int n_in,
                              void* d_out, int out_size, void* d_ws, size_t ws_size,
                              hipStream_t stream) {
  (void)in_sizes; (void)n_in; (void)out_size; (void)ws_size;
  const int* tokens = (const int*)d_in[0];
  const int* lengths = (const int*)d_in[1];
  const float* W_ih = (const float*)d_in[2];
  const float* W_hh = (const float*)d_in[3];
  const float* b_ih = (const float*)d_in[4];
  const float* b_hh = (const float*)d_in[5];
  const float* fc_w = (const float*)d_in[6];
  const float* fc_b = (const float*)d_in[7];
  float* out = (float*)d_out;
  int* flags = (int*)d_ws;                                        // 16 KB
  unsigned short* hglob = (unsigned short*)((char*)d_ws + 16384); // 128 KB double-buffer

  prep_kernel<<<16, 256, 0, stream>>>(flags, out);
  lstm_wave<<<NG * WPG, NT, 0, stream>>>(tokens, lengths, W_ih, W_hh, b_ih, b_hh,
                                         fc_w, fc_b, out, flags, hglob);
}

// Round 3
// 11299.200 us; speedup vs baseline: 1.2240x; 1.2240x over previous
//
#include <hip/hip_runtime.h>

// Packed-LSTM (B=64, S=2048, H=512, V=25) + linear head — round 3.
// Round-2 structure (256 wave-autonomous WGs, W_hh in VGPRs, zero barriers in
// the step loop) with the sync contention fixed:
//   - flags polled RELAXED (no per-iteration buffer_inv) + s_sleep backoff;
//   - flags packed 64/group (4 cachelines) so a wave poll is 4 LLC requests;
//   - h staged via relaxed agent ATOMIC loads (LLC-serialized, no fence
//     needed: they issue after the flag hit, producer released before flag).

#define VOCAB 25
#define HIDDEN 512
#define BATCH 64
#define SEQ 2048
#define GB 16   // batches per group
#define NG 4    // groups
#define WPG 64  // wave-WGs per group
#define UPW 8   // hidden units per WG
#define NT 64

typedef short s16x8 __attribute__((ext_vector_type(8)));
typedef float f32x4 __attribute__((ext_vector_type(4)));

__device__ inline unsigned short f2bf(float x) {
  unsigned u = __float_as_uint(x);
  u += 0x7fffu + ((u >> 16) & 1u);  // RNE
  return (unsigned short)(u >> 16);
}
__device__ inline float sigf(float x) { return 1.0f / (1.0f + __expf(-x)); }
__device__ inline float tanh_fast(float x) { return 2.0f / (1.0f + __expf(-2.0f * x)) - 1.0f; }

__global__ void prep_kernel(int* flags, float* out) {
  const int i = blockIdx.x * blockDim.x + threadIdx.x;
  if (i < NG * WPG) flags[i] = 0;
  if (i < BATCH) out[i] = 0.f;
}

__global__ __launch_bounds__(NT, 1) void lstm_wave(
    const int* __restrict__ tokens, const int* __restrict__ lengths,
    const float* __restrict__ W_ih, const float* __restrict__ W_hh,
    const float* __restrict__ b_ih, const float* __restrict__ b_hh,
    const float* __restrict__ fc_w, const float* __restrict__ fc_b,
    float* __restrict__ out, int* flags, unsigned short* hglob) {
  const int tid = threadIdx.x;  // == lane
  const int bid = blockIdx.x;
  // XCD swizzle: group g on XCDs {2g,2g+1}
  const int x = bid & 7;
  const int g = x >> 1;                       // 0..3
  const int w = ((bid >> 3) << 1) | (x & 1);  // 0..63

  __shared__ int lenAll[BATCH];
  __shared__ int order_[BATCH];
  __shared__ int gIdxS[GB];
  __shared__ int gLenS[GB];
  __shared__ float xgt[VOCAB][33];   // input projection for this slice (rl = gate*8+unit)
  __shared__ float gatesS[32][17];   // D transpose scratch [rl][batch]

  lenAll[tid] = lengths[tid];
  __syncthreads();
  {  // stable argsort(-lengths)
    const int L = lenAll[tid];
    int r = 0;
    for (int j = 0; j < BATCH; ++j) {
      const int lj = lenAll[j];
      r += ((lj > L) || (lj == L && j < tid)) ? 1 : 0;
    }
    order_[r] = tid;
  }
  __syncthreads();
  if (tid < GB) {
    const int oi = order_[g * GB + tid];
    gIdxS[tid] = oi;
    gLenS[tid] = lenAll[oi];
  }
  for (int i = tid; i < VOCAB * 32; i += NT) {
    const int v = i >> 5, rl = i & 31;  // rl: gate = rl>>3, unit = rl&7
    const int rg = (rl >> 3) * HIDDEN + w * UPW + (rl & 7);
    xgt[v][rl] = W_ih[rg * VOCAB + v] + b_ih[rg] + b_hh[rg];
  }
  __syncthreads();

  const int m16 = tid & 15, quad = tid >> 4;  // MFMA lane roles
  const int cb = tid >> 2, cq = tid & 3;      // cell roles: batch, unit-pair
  const int u0 = 2 * cq;
  const int T = gLenS[0];
  const int myLen = gLenS[cb];
  const int* tokPtr = tokens + (size_t)gIdxS[cb] * SEQ;

  // B fragments: 2 n-tiles x 16 k-chunks, bf16 in VGPRs (128 VGPRs/lane)
  s16x8 Bf[2][16];
#pragma unroll
  for (int tile = 0; tile < 2; ++tile) {
    const int rl = tile * 16 + m16;
    const int rg = (rl >> 3) * HIDDEN + w * UPW + (rl & 7);
    const float* wr = W_hh + (size_t)rg * HIDDEN;
#pragma unroll
    for (int kt = 0; kt < 16; ++kt) {
      const float* p = wr + kt * 32 + quad * 8;
#pragma unroll
      for (int e = 0; e < 8; ++e) Bf[tile][kt][e] = (short)f2bf(p[e]);
    }
  }

  float c0 = 0.f, c1 = 0.f, h0 = 0.f, h1 = 0.f;
  int* myFlag = flags + g * WPG + w;      // packed: 64 flags/group = 4 cachelines
  int* pollFlag = flags + g * WPG + tid;  // lane l polls slice l's flag
  const size_t grpStride = (size_t)GB * HIDDEN;  // shorts

  union QA { unsigned long long q[2]; s16x8 v; };

  for (int t = 0; t < T; ++t) {
    const int tok = tokPtr[t];
    s16x8 A[16];
    if (t > 0) {
      for (;;) {  // RELAXED poll: no buffer_inv, LLC-serialized, 4 lines/wave
        const int v = __hip_atomic_load(pollFlag, __ATOMIC_RELAXED, __HIP_MEMORY_SCOPE_AGENT);
        if (__all(v >= t)) break;
        __builtin_amdgcn_s_sleep(1);
      }
      // h loads: relaxed agent atomics (bypass L1/L2). Issued after the flag
      // hit; producer's release put h in LLC before the flag -> fresh data.
      const unsigned long long* hb =
          (const unsigned long long*)(hglob + ((size_t)(t & 1) * NG + g) * grpStride +
                                      (size_t)m16 * HIDDEN + quad * 8);
#pragma unroll
      for (int kt = 0; kt < 16; ++kt) {
        QA qa;
        qa.q[0] = __hip_atomic_load(hb + kt * 8, __ATOMIC_RELAXED, __HIP_MEMORY_SCOPE_AGENT);
        qa.q[1] = __hip_atomic_load(hb + kt * 8 + 1, __ATOMIC_RELAXED, __HIP_MEMORY_SCOPE_AGENT);
        A[kt] = qa.v;
      }
    } else {
#pragma unroll
      for (int kt = 0; kt < 16; ++kt) A[kt] = (s16x8){0, 0, 0, 0, 0, 0, 0, 0};
    }

    f32x4 a0a = {0.f, 0.f, 0.f, 0.f}, a0b = {0.f, 0.f, 0.f, 0.f};
    f32x4 a1a = {0.f, 0.f, 0.f, 0.f}, a1b = {0.f, 0.f, 0.f, 0.f};
#pragma unroll
    for (int kt = 0; kt < 16; kt += 2) {  // 4 independent accumulation chains
      a0a = __builtin_amdgcn_mfma_f32_16x16x32_bf16(A[kt], Bf[0][kt], a0a, 0, 0, 0);
      a1a = __builtin_amdgcn_mfma_f32_16x16x32_bf16(A[kt], Bf[1][kt], a1a, 0, 0, 0);
      a0b = __builtin_amdgcn_mfma_f32_16x16x32_bf16(A[kt + 1], Bf[0][kt + 1], a0b, 0, 0, 0);
      a1b = __builtin_amdgcn_mfma_f32_16x16x32_bf16(A[kt + 1], Bf[1][kt + 1], a1b, 0, 0, 0);
    }
    const f32x4 d0 = a0a + a0b, d1 = a1a + a1b;
    // D layout: row(batch)=quad*4+v, col(gate-row)=m16. In-wave transpose via LDS.
#pragma unroll
    for (int v = 0; v < 4; ++v) {
      gatesS[m16][quad * 4 + v] = d0[v];
      gatesS[16 + m16][quad * 4 + v] = d1[v];
    }
    const float* xr = &xgt[tok][0];
    float p0[4], p1[4];
#pragma unroll
    for (int gg = 0; gg < 4; ++gg) {
      p0[gg] = gatesS[gg * 8 + u0][cb] + xr[gg * 8 + u0];
      p1[gg] = gatesS[gg * 8 + u0 + 1][cb] + xr[gg * 8 + u0 + 1];
    }
    if (t < myLen) {  // freeze state past sequence end
      float ii = sigf(p0[0]), ff = sigf(p0[1]), gv = tanh_fast(p0[2]), oo = sigf(p0[3]);
      c0 = ff * c0 + ii * gv;
      h0 = oo * tanh_fast(c0);
      ii = sigf(p1[0]); ff = sigf(p1[1]); gv = tanh_fast(p1[2]); oo = sigf(p1[3]);
      c1 = ff * c1 + ii * gv;
      h1 = oo * tanh_fast(c1);
    }
    if (t + 1 < T) {
      const unsigned val = (unsigned)f2bf(h0) | ((unsigned)f2bf(h1) << 16);
      unsigned* hp = (unsigned*)(hglob + ((size_t)((t + 1) & 1) * NG + g) * grpStride +
                                 (size_t)cb * HIDDEN + w * UPW + u0);
      __hip_atomic_store(hp, val, __ATOMIC_RELAXED, __HIP_MEMORY_SCOPE_AGENT);
      if (tid == 0)  // release: wave-wide vmcnt drain orders all lanes' h stores
        __hip_atomic_store(myFlag, t + 1, __ATOMIC_RELEASE, __HIP_MEMORY_SCOPE_AGENT);
    }
  }

  // out[g*16+b] = h . fc_w + fc_b (sorted order)
  float part = h0 * fc_w[w * UPW + u0] + h1 * fc_w[w * UPW + u0 + 1];
  part += __shfl_xor(part, 1);
  part += __shfl_xor(part, 2);
  if (cq == 0) {
    if (w == 0) part += fc_b[0];
    atomicAdd(&out[g * GB + cb], part);
  }
}

extern "C" void kernel_launch(void* const* d_in, const int* in_sizes, int n_in,
                              void* d_out, int out_size, void* d_ws, size_t ws_size,
                              hipStream_t stream) {
  (void)in_sizes; (void)n_in; (void)out_size; (void)ws_size;
  const int* tokens = (const int*)d_in[0];
  const int* lengths = (const int*)d_in[1];
  const float* W_ih = (const float*)d_in[2];
  const float* W_hh = (const float*)d_in[3];
  const float* b_ih = (const float*)d_in[4];
  const float* b_hh = (const float*)d_in[5];
  const float* fc_w = (const float*)d_in[6];
  const float* fc_b = (const float*)d_in[7];
  float* out = (float*)d_out;
  int* flags = (int*)d_ws;                                        // 1 KB used (packed)
  unsigned short* hglob = (unsigned short*)((char*)d_ws + 16384); // 128 KB double-buffer

  prep_kernel<<<16, 256, 0, stream>>>(flags, out);
  lstm_wave<<<NG * WPG, NT, 0, stream>>>(tokens, lengths, W_ih, W_hh, b_ih, b_hh,
                                         fc_w, fc_b, out, flags, hglob);
}